// Round 8
// baseline (159.401 us; speedup 1.0000x reference)
//
#include <hip/hip_runtime.h>
#include <hip/hip_bf16.h>

// B=2, M=2048, HID=1024, NH=16, D=64.  No softmax in the reference, so
//   out = ((h Wq^T)(h Wk^T)^T (h Wv^T)) Wo^T
// r19 reassociates THREE times (one more than before):
//   S_bh  = K_h^T V_h                      (64x64 per (b,h))
//   R_b[k, h64+j] = sum_d Wq[h64+d,k] S_bh[d,j]      (fold Wq through S)
//   X_b[n, k]     = sum_hj Wo[n,hj] R_b[k,hj]        (= NT(Wo, R_b))
//   out_b         = h_b @ X_b^T                      (= NT(hb, X_b))
// so Q is NEVER materialized: gemm1 computes only K,V (N=2048 not 3072).
// MFMA work: 17.2 (KV) + 4.3 (X) + 8.6 (out) = 30.1 GFLOP vs 34.4 before,
// and the dominant kernel shrinks 33%.
//
// Dtypes: inputs fp32, d_out fp32; internal bf16 with fp32 accumulate.
// One extra bf16 intermediate (R) vs r18: absmax expected ~6-8 (thr 11.68).
//
// Round-19 rationale: r15-r18 tried four schedule/locality/occupancy
// variants of the big GEMMs; all within +-3us -> the structure is at its
// plateau (~30-35% MfmaUtil).  The remaining lever is algebraic FLOP
// reduction, not efficiency.
// Lessons kept: no dense-reduction atomics (r6->r7); never trade
// high-occupancy FLOPs for low-occupancy FLOPs (r8); price redundant
// re-reads by XCD locality (r10); vmcnt waits are per-wave -- wait must
// precede a barrier (r12); count LDS bytes per phase (r13); grid must
// cover all 256 CUs (r14); don't serialize LDS and MFMA with explicit
// drains (r15); size the per-XCD L2 working set (r16); in-block schedule
// tweaks can't fix lockstep stalls (r17); when 4 structural variants tie,
// stop tuning and cut work (r18).
//
// Pipeline:
//   0. prep: h->hb, Wk|Wv->wcat (2048x1024), Wo->wob   (bf16)
//   1. KVb = hb @ wcat^T         (4096x2048 bf16)           [gemm512<256>]
//   2. Spart[bh,c] = K^T V partial over 128 rows            [VALU]
//   2b. St[bh][j][d] = sum_c Spart  (TRANSPOSED store)      [BW]
//   3. R[b][k][hj] = Wq-fold of S   (t_kernel clone)        [VALU]
//   4. X[b][n][k] = NT(wob, R_b)    (1024x1024 per b)       [gemmX 256thr]
//   5. out = NT(hb, X_b)            (4096x1024 fp32)        [gemm512<128>]

typedef unsigned short u16;
typedef unsigned int u32;
typedef __attribute__((ext_vector_type(8))) short bf16x8;
typedef __attribute__((ext_vector_type(4))) float f32x4;

__device__ __forceinline__ void async_copy16(void* lds, const void* g) {
  __builtin_amdgcn_global_load_lds((const __attribute__((address_space(1))) void*)g,
                                   (__attribute__((address_space(3))) void*)lds,
                                   16, 0, 0);
}

__device__ __forceinline__ u16 f2bf(float f) {
  union { __hip_bfloat16 h; u16 u; } c;
  c.h = __float2bfloat16(f);
  return c.u;
}
__device__ __forceinline__ float bflo(u32 w) {
  union { u32 u; float f; } c; c.u = w << 16; return c.f;
}
__device__ __forceinline__ float bfhi(u32 w) {
  union { u32 u; float f; } c; c.u = w & 0xFFFF0000u; return c.f;
}
__device__ __forceinline__ ushort4 cvt4(float4 v) {
  ushort4 o; o.x = f2bf(v.x); o.y = f2bf(v.y); o.z = f2bf(v.z); o.w = f2bf(v.w);
  return o;
}

template <int N> __device__ __forceinline__ void vw() {
  if constexpr (N == 8)      asm volatile("s_waitcnt vmcnt(8)" ::: "memory");
  else if constexpr (N == 6) asm volatile("s_waitcnt vmcnt(6)" ::: "memory");
  else if constexpr (N == 4) asm volatile("s_waitcnt vmcnt(4)" ::: "memory");
  else if constexpr (N == 3) asm volatile("s_waitcnt vmcnt(3)" ::: "memory");
  else if constexpr (N == 2) asm volatile("s_waitcnt vmcnt(2)" ::: "memory");
  else if constexpr (N == 0) asm volatile("s_waitcnt vmcnt(0)" ::: "memory");
}

// ---------------------------------------------------------------- prep ------
// h->hb, Wk->wcat[0:1024), Wv->wcat[1024:2048), Wo->wob.  All bf16.
__global__ __launch_bounds__(256) void prep(const float4* __restrict__ h,
                                            const float4* __restrict__ wk,
                                            const float4* __restrict__ wv,
                                            const float4* __restrict__ wo,
                                            ushort4* __restrict__ hb,
                                            ushort4* __restrict__ wcat,
                                            ushort4* __restrict__ wob) {
  int i = blockIdx.x * 256 + threadIdx.x;  // float4 units
  if (i < 1048576) { hb[i] = cvt4(h[i]); return; }          // h: 4096x1024
  i -= 1048576;
  if (i < 262144) { wcat[i] = cvt4(wk[i]); return; }
  i -= 262144;
  if (i < 262144) { wcat[262144 + i] = cvt4(wv[i]); return; }
  i -= 262144;
  wob[i] = cvt4(wo[i]);
}

// ------------------------------ BK=32 4-buffer counted-vmcnt NT GEMM --------
// 512-thr form (r16-verified).  C[m,n] = sum_k A[m*lda+k] * B[n*1024+k],
// M=4096, K=1024, BM=128.  grid 256 = 32 m x 8 n; 8 waves (2x4).
// Phase: {MI+NI ds_read_b128 | stage kt+3 | MFMA (dataflow-interleaved,
// setprio) | lgkmcnt(0) | vw<2V> | s_barrier | sched_barrier}.

#define NOPW ((void)0)

#define PHASE(KT, DO_STAGE, VWAIT)                                           \
  do {                                                                       \
    const u16* Ab = &Als[(KT) & 3][wm * 32 + aoff];                          \
    const u16* Bb = &Bls[(KT) & 3][wn * 32 + aoff];                          \
    bf16x8 af[MI], bv[NI];                                                   \
    _Pragma("unroll") for (int i = 0; i < MI; ++i)                           \
        af[i] = *(const bf16x8*)(Ab + i * 512);                              \
    _Pragma("unroll") for (int j = 0; j < NI; ++j)                           \
        bv[j] = *(const bf16x8*)(Bb + j * 512);                              \
    DO_STAGE;                                                                \
    __builtin_amdgcn_s_setprio(1);                                           \
    _Pragma("unroll") for (int i = 0; i < MI; ++i)                           \
        _Pragma("unroll") for (int j = 0; j < NI; ++j)                       \
            acc[i][j] = __builtin_amdgcn_mfma_f32_16x16x32_bf16(             \
                af[i], bv[j], acc[i][j], 0, 0, 0);                           \
    __builtin_amdgcn_s_setprio(0);                                           \
    asm volatile("s_waitcnt lgkmcnt(0)" ::: "memory");                       \
    VWAIT;                                                                   \
    __builtin_amdgcn_s_barrier();                                            \
    __builtin_amdgcn_sched_barrier(0);                                       \
  } while (0)

template <bool BF16_OUT, int BN>
__global__ __launch_bounds__(512, 2) void gemm512(const u16* __restrict__ A,
                                                  int lda,
                                                  const u16* __restrict__ B0,
                                                  const u16* __restrict__ B1,
                                                  void* __restrict__ Cv,
                                                  int N) {
  constexpr int SA = 1;              // A staging insts/thread (BM=128)
  constexpr int SB = BN / 128;       // B staging insts/thread
  constexpr int V  = SA + SB;
  constexpr int MI = 4;              // 64-row wave half
  constexpr int NI = BN / 4 / 16;

  __shared__ u16 Als[4][128 * 32];
  __shared__ u16 Bls[4][BN * 32];
  const int t = threadIdx.x;
  const int lane = t & 63;
  const int wave = t >> 6;                 // 0..7
  const int wm = (wave >> 2) * 64;         // 0 / 64
  const int wn = (wave & 3) * (BN / 4);
  const int lrow = lane & 15;
  const int quad = lane >> 4;

  // XCD-owns-n-panel mapping (r17): bid&7 ~ XCD; B panel L2-resident.
  const int bid = blockIdx.x;
  const int m0 = (bid >> 3) * 128;
  const int n0 = (bid & 7) * BN;
  const u16* B = (B1 != nullptr && m0 >= 2048) ? B1 : B0;

  // staging: one inst = 16 rows x 32 k; lane l -> row +(l>>2),
  // LDS slot l&3 holds global k-granule (l&3)^((l>>3)&3)  (linear dest).
  const int srow = lane >> 2;
  const int sgk  = (lane & 3) ^ ((lane >> 3) & 3);
  const u16* Ag = A + (size_t)(m0 + wave * (SA * 16) + srow) * lda + sgk * 8;
  const u16* Bg = B + (size_t)(n0 + wave * (SB * 16) + srow) * 1024 + sgk * 8;

  // read swizzle: slot of granule `quad` at row r is quad^((r>>1)&3);
  // row bases are multiples of 16 -> (r>>1)&3 == (lrow>>1)&3.
  const int swz = (lrow >> 1) & 3;
  const int aoff = lrow * 32 + ((quad ^ swz) << 3);

  f32x4 acc[MI][NI];
#pragma unroll
  for (int i = 0; i < MI; ++i)
#pragma unroll
    for (int j = 0; j < NI; ++j) acc[i][j] = {0.f, 0.f, 0.f, 0.f};

  auto stage = [&](int kt) {
    const int buf = kt & 3;
#pragma unroll
    for (int j = 0; j < SA; ++j) {
      const int ch = wave * SA + j;
      async_copy16(&Als[buf][ch * 512 + lane * 8],
                   Ag + (size_t)(j * 16) * lda + kt * 32);
    }
#pragma unroll
    for (int j = 0; j < SB; ++j) {
      const int ch = wave * SB + j;
      async_copy16(&Bls[buf][ch * 512 + lane * 8],
                   Bg + (size_t)(j * 16) * 1024 + kt * 32);
    }
  };

  stage(0); stage(1); stage(2);
  vw<2 * V>();
  __builtin_amdgcn_s_barrier();
  __builtin_amdgcn_sched_barrier(0);

#pragma unroll 1
  for (int kt = 0; kt < 29; ++kt) {
    PHASE(kt, stage(kt + 3), vw<2 * V>());
  }
  PHASE(29, NOPW, vw<V>());
  PHASE(30, NOPW, vw<0>());
  PHASE(31, NOPW, NOPW);

  // C/D layout (verified m89/m91): col = lane&15, row = (lane>>4)*4 + r
  const int crow0 = m0 + wm + quad * 4;
  const int ccol0 = n0 + wn + lrow;
#pragma unroll
  for (int mf = 0; mf < MI; ++mf)
#pragma unroll
    for (int nf = 0; nf < NI; ++nf)
#pragma unroll
      for (int r = 0; r < 4; ++r) {
        const size_t idx = (size_t)(crow0 + mf * 16 + r) * N + ccol0 + nf * 16;
        if (BF16_OUT) ((u16*)Cv)[idx]   = f2bf(acc[mf][nf][r]);
        else          ((float*)Cv)[idx] = acc[mf][nf][r];
      }
}

// ---------------- small batched NT GEMM: X_b = NT(wob, R_b) -----------------
// 256-thr form (r18-verified): BM=64, BN=128, 3-buffer depth-2.
// grid 256 = 2 batch x 16 m x 8 n.  C bf16.
__global__ __launch_bounds__(256, 2) void gemmX(const u16* __restrict__ A,
                                                const u16* __restrict__ B0,
                                                u16* __restrict__ C0) {
  constexpr int SA = 1, SB = 2, V = 3;  // BM/64, BN/64
  constexpr int MI = 4, NI = 2;         // 64 rows, 32 cols per wave

  __shared__ u16 Als[3][64 * 32];
  __shared__ u16 Bls[3][128 * 32];
  const int t = threadIdx.x;
  const int lane = t & 63;
  const int wave = t >> 6;               // 0..3
  const int wn = wave * 32;
  const int lrow = lane & 15;
  const int quad = lane >> 4;

  const int bid = blockIdx.x;
  const int b  = bid >> 7;
  const int m0 = ((bid >> 3) & 15) * 64;
  const int n0 = (bid & 7) * 128;
  const u16* B = B0 + (size_t)b * 1048576;
  u16* C = C0 + (size_t)b * 1048576;

  const int srow = lane >> 2;
  const int sgk  = (lane & 3) ^ ((lane >> 3) & 3);
  const u16* Ag = A + (size_t)(m0 + srow) * 1024 + sgk * 8;
  const u16* Bg = B + (size_t)(n0 + srow) * 1024 + sgk * 8;

  const int swz = (lrow >> 1) & 3;
  const int aoff = lrow * 32 + ((quad ^ swz) << 3);

  f32x4 acc[MI][NI];
#pragma unroll
  for (int i = 0; i < MI; ++i)
#pragma unroll
    for (int j = 0; j < NI; ++j) acc[i][j] = {0.f, 0.f, 0.f, 0.f};

  auto stage = [&](int kt) {
    const int buf = kt % 3;
#pragma unroll
    for (int j = 0; j < SA; ++j) {
      const int ch = j * 4 + wave;
      async_copy16(&Als[buf][ch * 512 + lane * 8],
                   Ag + (size_t)(ch * 16) * 1024 + kt * 32);
    }
#pragma unroll
    for (int j = 0; j < SB; ++j) {
      const int ch = j * 4 + wave;
      async_copy16(&Bls[buf][ch * 512 + lane * 8],
                   Bg + (size_t)(ch * 16) * 1024 + kt * 32);
    }
  };

  stage(0); stage(1);
  vw<V>();
  __builtin_amdgcn_s_barrier();
  __builtin_amdgcn_sched_barrier(0);

#pragma unroll 1
  for (int kt = 0; kt < 30; ++kt) {
    // PHASE macro reads Als at [wm*32+aoff]; here wave spans all 64 rows
    // (wm=0) and owns cols wn..wn+31.
    const int wm = 0; (void)wm;
    do {
      const u16* Ab = &Als[kt % 3][aoff];
      const u16* Bb = &Bls[kt % 3][wn * 32 + aoff];
      bf16x8 af[MI], bv[NI];
#pragma unroll
      for (int i = 0; i < MI; ++i) af[i] = *(const bf16x8*)(Ab + i * 512);
#pragma unroll
      for (int j = 0; j < NI; ++j) bv[j] = *(const bf16x8*)(Bb + j * 512);
      stage(kt + 2);
      __builtin_amdgcn_s_setprio(1);
#pragma unroll
      for (int i = 0; i < MI; ++i)
#pragma unroll
        for (int j = 0; j < NI; ++j)
          acc[i][j] = __builtin_amdgcn_mfma_f32_16x16x32_bf16(
              af[i], bv[j], acc[i][j], 0, 0, 0);
      __builtin_amdgcn_s_setprio(0);
      asm volatile("s_waitcnt lgkmcnt(0)" ::: "memory");
      vw<V>();
      __builtin_amdgcn_s_barrier();
      __builtin_amdgcn_sched_barrier(0);
    } while (0);
  }
  // tails
  for (int kt = 30; kt < 32; ++kt) {
    const u16* Ab = &Als[kt % 3][aoff];
    const u16* Bb = &Bls[kt % 3][wn * 32 + aoff];
    bf16x8 af[MI], bv[NI];
#pragma unroll
    for (int i = 0; i < MI; ++i) af[i] = *(const bf16x8*)(Ab + i * 512);
#pragma unroll
    for (int j = 0; j < NI; ++j) bv[j] = *(const bf16x8*)(Bb + j * 512);
    __builtin_amdgcn_s_setprio(1);
#pragma unroll
    for (int i = 0; i < MI; ++i)
#pragma unroll
      for (int j = 0; j < NI; ++j)
        acc[i][j] = __builtin_amdgcn_mfma_f32_16x16x32_bf16(
            af[i], bv[j], acc[i][j], 0, 0, 0);
    __builtin_amdgcn_s_setprio(0);
    asm volatile("s_waitcnt lgkmcnt(0)" ::: "memory");
    if (kt == 30) vw<0>();
    __builtin_amdgcn_s_barrier();
    __builtin_amdgcn_sched_barrier(0);
  }

  const int crow0 = m0 + quad * 4;
  const int ccol0 = n0 + wn + lrow;
#pragma unroll
  for (int mf = 0; mf < MI; ++mf)
#pragma unroll
    for (int nf = 0; nf < NI; ++nf)
#pragma unroll
      for (int r = 0; r < 4; ++r)
        C[(size_t)(crow0 + mf * 16 + r) * 1024 + ccol0 + nf * 16] =
            f2bf(acc[mf][nf][r]);
}

// --------------------------------------------- Spart = partial K^T V --------
// KVb: (4096, 2048) bf16; cols [0,1024)=K, [1024,2048)=V.
__global__ __launch_bounds__(256) void s_kernel(const u16* __restrict__ KV,
                                                float* __restrict__ Spart) {
  const int bh = blockIdx.x;
  const int b = bh >> 4, hh = bh & 15;
  const int row0 = b * 2048 + blockIdx.y * 128;
  const u16* Kg = KV + (size_t)row0 * 2048 + hh * 64;

  __shared__ float Ks[64][64];
  __shared__ float Vs[64][64];
  const int t = threadIdx.x;
  const int lr = t >> 2;
  const int lc = (t & 3) * 16;
  const int d1 = (t >> 4) * 4;
  const int d2 = (t & 15) * 4;

  float acc[4][4] = {};

  for (int r0 = 0; r0 < 128; r0 += 64) {
    const u16* kp = Kg + (size_t)(r0 + lr) * 2048 + lc;
    const uint4 kw0 = *(const uint4*)kp;
    const uint4 kw1 = *(const uint4*)(kp + 8);
    const uint4 vw0 = *(const uint4*)(kp + 1024);  // V = K + 1024 cols
    const uint4 vw1 = *(const uint4*)(kp + 1032);
    __syncthreads();  // prev-iter readers done
    float* kd = &Ks[lr][lc];
    *(float4*)(kd)      = float4{bflo(kw0.x), bfhi(kw0.x), bflo(kw0.y), bfhi(kw0.y)};
    *(float4*)(kd + 4)  = float4{bflo(kw0.z), bfhi(kw0.z), bflo(kw0.w), bfhi(kw0.w)};
    *(float4*)(kd + 8)  = float4{bflo(kw1.x), bfhi(kw1.x), bflo(kw1.y), bfhi(kw1.y)};
    *(float4*)(kd + 12) = float4{bflo(kw1.z), bfhi(kw1.z), bflo(kw1.w), bfhi(kw1.w)};
    float* vd = &Vs[lr][lc];
    *(float4*)(vd)      = float4{bflo(vw0.x), bfhi(vw0.x), bflo(vw0.y), bfhi(vw0.y)};
    *(float4*)(vd + 4)  = float4{bflo(vw0.z), bfhi(vw0.z), bflo(vw0.w), bfhi(vw0.w)};
    *(float4*)(vd + 8)  = float4{bflo(vw1.x), bfhi(vw1.x), bflo(vw1.y), bfhi(vw1.y)};
    *(float4*)(vd + 12) = float4{bflo(vw1.z), bfhi(vw1.z), bflo(vw1.w), bfhi(vw1.w)};
    __syncthreads();
#pragma unroll
    for (int r = 0; r < 64; ++r) {
      float kv[4], vv[4];
      *(float4*)kv = *(const float4*)&Ks[r][d1];
      *(float4*)vv = *(const float4*)&Vs[r][d2];
#pragma unroll
      for (int i = 0; i < 4; ++i)
#pragma unroll
        for (int j = 0; j < 4; ++j) acc[i][j] += kv[i] * vv[j];
    }
  }
  float* Sp = Spart + ((size_t)bh * 16 + blockIdx.y) * 4096;
#pragma unroll
  for (int i = 0; i < 4; ++i)
    *(float4*)&Sp[(d1 + i) * 64 + d2] =
        float4{acc[i][0], acc[i][1], acc[i][2], acc[i][3]};
}

// ----------------------------- St[bh][j][d] = sum_c Spart[bh,c][d][j] -------
// Transposed store so r_kernel's LDS loads stay linear.
__global__ __launch_bounds__(256) void reduce_s(const float4* __restrict__ Spart,
                                                float* __restrict__ St) {
  const int g = blockIdx.x * 256 + threadIdx.x;  // 0..32767
  const int bh = g >> 10, j4 = g & 1023;
  const float4* p = Spart + (size_t)bh * 16384 + j4;
  float4 a = {0.f, 0.f, 0.f, 0.f};
#pragma unroll
  for (int c = 0; c < 16; ++c) {
    const float4 v = p[(size_t)c * 1024];
    a.x += v.x; a.y += v.y; a.z += v.z; a.w += v.w;
  }
  const int d = j4 >> 4;            // flat = 4*j4 = d*64 + j0
  const int j0 = (4 * j4) & 63;
  float* o = St + (size_t)bh * 4096 + d;
  o[(size_t)(j0 + 0) * 64] = a.x;
  o[(size_t)(j0 + 1) * 64] = a.y;
  o[(size_t)(j0 + 2) * 64] = a.z;
  o[(size_t)(j0 + 3) * 64] = a.w;
}

// ------------------- R[b][k][h64+j] = sum_d Wq[h64+d,k] * S_bh[d,j] ---------
// t_kernel clone: Ss[j][d] <- St (linear); Ws[kl][d] <- Wq 64x128 block,
// transposed in LDS.  grid (8 kchunks, 16 h, 2 b).
__global__ __launch_bounds__(256) void r_kernel(const float* __restrict__ St,
                                                const float* __restrict__ Wq,
                                                u16* __restrict__ R) {
  const int k0 = blockIdx.x * 128;
  const int hh = blockIdx.y;
  const int b  = blockIdx.z;
  __shared__ float Ss[64][68];
  __shared__ float Ws[128][68];
  const int t = threadIdx.x;
  {
    const float* sg = St + (size_t)(b * 16 + hh) * 4096 + (t >> 2) * 64 + (t & 3) * 16;
    float* sd = &Ss[t >> 2][(t & 3) * 16];
#pragma unroll
    for (int i = 0; i < 4; ++i) *(float4*)(sd + 4 * i) = *(const float4*)(sg + 4 * i);
    // Ws[kl][d] = Wq[h64+d, k0+kl]: thread t reads row d=t>>2, col seg
    // (t&3)*32, 8 float4s; scatters 4 scalars each (transpose in LDS).
    const int d = t >> 2;
    const int cs = (t & 3) * 32;
    const float* wg = Wq + (size_t)(hh * 64 + d) * 1024 + k0 + cs;
#pragma unroll
    for (int i = 0; i < 8; ++i) {
      const float4 v = *(const float4*)(wg + 4 * i);
      Ws[cs + 4 * i + 0][d] = v.x;
      Ws[cs + 4 * i + 1][d] = v.y;
      Ws[cs + 4 * i + 2][d] = v.z;
      Ws[cs + 4 * i + 3][d] = v.w;
    }
  }
  __syncthreads();

  const int tj = (t >> 4) * 4;  // j = tj..tj+3
  const int tk = t & 15;        // k = k0 + tk + 16q
  float acc[4][8] = {};
  for (int dd = 0; dd < 64; dd += 4) {
    float4 sv[4], wv[8];
#pragma unroll
    for (int i = 0; i < 4; ++i) sv[i] = *(const float4*)&Ss[tj + i][dd];
#pragma unroll
    for (int q = 0; q < 8; ++q) wv[q] = *(const float4*)&Ws[tk + 16 * q][dd];
#pragma unroll
    for (int i = 0; i < 4; ++i)
#pragma unroll
      for (int q = 0; q < 8; ++q)
        acc[i][q] += sv[i].x * wv[q].x + sv[i].y * wv[q].y +
                     sv[i].z * wv[q].z + sv[i].w * wv[q].w;
  }

  u16* rp = R + (size_t)b * 1048576;
#pragma unroll
  for (int q = 0; q < 8; ++q) {
    const int k = k0 + tk + 16 * q;
    ushort4 o;
    o.x = f2bf(acc[0][q]); o.y = f2bf(acc[1][q]);
    o.z = f2bf(acc[2][q]); o.w = f2bf(acc[3][q]);
    *(ushort4*)&rp[(size_t)k * 1024 + hh * 64 + tj] = o;
  }
}

// ---------------------------------------------------------------------------
extern "C" void kernel_launch(void* const* d_in, const int* in_sizes, int n_in,
                              void* d_out, int out_size, void* d_ws, size_t ws_size,
                              hipStream_t stream) {
  const float* h  = (const float*)d_in[0];  // (4096, 1024) fp32
  // d_in[1] = key_pe: dead branch in reference, unused.
  const float* Wq = (const float*)d_in[2];
  const float* Wk = (const float*)d_in[3];
  const float* Wv = (const float*)d_in[4];
  const float* Wo = (const float*)d_in[5];

  char* ws = (char*)d_ws;
  u16*   hb    = (u16*)(ws);                    // 4096*1024*2 = 8 MiB @ 0
  u16*   wcat  = (u16*)(ws + (8ull  << 20));    // 2048*1024*2 = 4 MiB
  u16*   wob   = (u16*)(ws + (12ull << 20));    // 1024*1024*2 = 2 MiB
  u16*   KVb   = (u16*)(ws + (16ull << 20));    // 4096*2048*2 = 16 MiB
  float* St    = (float*)(ws + (40ull << 20));  // 32*64*64*4  = 0.5 MiB
  u16*   R     = (u16*)(ws + (41ull << 20));    // 2*1024*1024*2 = 4 MiB
  u16*   X     = (u16*)(ws + (45ull << 20));    // 2*1024*1024*2 = 4 MiB
  float* Spart = (float*)(ws + (56ull << 20));  // 512*64*64*4 = 8 MiB
  // total ws use: 64 MiB (ws_size = 256 MiB)

  prep<<<7168, 256, 0, stream>>>((const float4*)h, (const float4*)Wk,
                                 (const float4*)Wv, (const float4*)Wo,
                                 (ushort4*)hb, (ushort4*)wcat, (ushort4*)wob);
  // KVb = hb @ wcat^T : (4096 x 2048), K=1024, 256 blocks, 8 waves
  gemm512<true, 256><<<256, 512, 0, stream>>>(hb, 1024, wcat, nullptr,
                                              KVb, 2048);
  s_kernel<<<dim3(32, 16), 256, 0, stream>>>(KVb, Spart);
  reduce_s<<<128, 256, 0, stream>>>((const float4*)Spart, St);
  r_kernel<<<dim3(8, 16, 2), 256, 0, stream>>>(St, Wq, R);
  // X_b = NT(wob, R_b): 2 x (1024 x 1024), K=1024; 256 blocks, 4 waves
  gemmX<<<256, 256, 0, stream>>>(wob, R, X);
  // out = NT(hb, X_b) : (4096 x 1024), K=1024, 256 blocks, 8 waves
  gemm512<false, 128><<<256, 512, 0, stream>>>(hb, 1024, X, X + 1048576,
                                               d_out, 1024);
}

// Round 9
// 152.793 us; speedup vs baseline: 1.0432x; 1.0432x over previous
//
#include <hip/hip_runtime.h>
#include <hip/hip_bf16.h>

// B=2, M=2048, HID=1024, NH=16, D=64.  No softmax in the reference, so
//   out = ((h Wq^T)(h Wk^T)^T (h Wv^T)) Wo^T
// reassociates twice:  S_{b,h} = K_h^T V_h  (64x64), and
//   out_b = Q_b @ T_b   with  T_b[h*64+d, n] = sum_j S_{b,h}[d,j] Wo[n, h*64+j]
//
// Dtypes: inputs fp32, d_out fp32; internal bf16 with fp32 accumulate.
//
// Round-20: r19's Q-fold (3rd reassociation) REGRESSED +8us: it cut 12% of
// FLOPs but added two kernels + intermediates to a pipeline whose GEMMs are
// WAIT-bound (r13: MfmaUtil 18.9%, ~70% wait) -- FLOP cuts only pay when
// compute-bound.  Reverted to the r15 pipeline (best measured, 151.5us).
// The wait is per-phase FIXED cost (barrier + vmcnt-drain latency) paid
// 32x/GEMM; r14 already showed phase-halving pays (64->32 was -13us).
// r20 halves again WITHOUT losing depth-2 prefetch: TWO K-tiles per phase,
// 5-buffer rotation:
//   phase p: reads tiles 2p,2p+1 (bufs %5), stages tiles 2p+3,2p+4
//   (bufs %5, all 4 distinct mod 5); ends lgkmcnt(0), vw<V>, barrier.
//   vw<V> drains exactly tiles 2p+2,2p+3 (next phase's), leaves 2p+4.
//   Prologue: stage 0,1,2, vw<V>, barrier.  Tail: p=14 stages 31 only,
//   vw<0>; p=15 bare.  WAR proof as r14.
// 16 phases, 48 MFMA/wave/phase.  LDS: gemm1 5x(8+24KB)=160KB exactly
// (1 block/CU, grid 256 = one full round); gemm2 5x16KB=80KB, lb(512,4)
// -> 2 blocks/CU possible.  Swizzle/staging/epilogue/mapping unchanged.
// Lessons kept: no dense-reduction atomics (r6->r7); never trade
// high-occupancy FLOPs for low-occupancy FLOPs (r8); price redundant
// re-reads by XCD locality (r10); vmcnt waits are per-wave -- wait must
// precede a barrier (r12); count LDS bytes per phase (r13); grid must
// cover all 256 CUs (r14); don't serialize LDS and MFMA with explicit
// drains (r15); size the per-XCD L2 working set (r16); in-block schedule
// tweaks can't fix lockstep stalls (r17); when variants tie, cut work not
// tune (r18); FLOP cuts don't pay in the wait-bound regime (r19).
//
// Pipeline:
//   0. prep: h->hb (bf16), Wq|Wk|Wv->wcat (bf16)
//   1. QKVb = hb @ wcat^T        (4096x3072 bf16)            [gemmP<384>]
//   2. Spart[bh,c] = K^T V partial over 128 rows             [VALU]
//   2b. S = sum_c Spart          (each line read once)       [BW]
//   3. Tt[b][n,k] = (S_h Wo_h^T)^T  (2 x 1024x1024 bf16)     [VALU]
//   4. out = Q @ Tt_b^T          (4096x1024 fp32 -> d_out)   [gemmP<128>]

typedef unsigned short u16;
typedef unsigned int u32;
typedef __attribute__((ext_vector_type(8))) short bf16x8;
typedef __attribute__((ext_vector_type(4))) float f32x4;

__device__ __forceinline__ void async_copy16(void* lds, const void* g) {
  __builtin_amdgcn_global_load_lds((const __attribute__((address_space(1))) void*)g,
                                   (__attribute__((address_space(3))) void*)lds,
                                   16, 0, 0);
}

__device__ __forceinline__ u16 f2bf(float f) {
  union { __hip_bfloat16 h; u16 u; } c;
  c.h = __float2bfloat16(f);
  return c.u;
}
__device__ __forceinline__ float bflo(u32 w) {
  union { u32 u; float f; } c; c.u = w << 16; return c.f;
}
__device__ __forceinline__ float bfhi(u32 w) {
  union { u32 u; float f; } c; c.u = w & 0xFFFF0000u; return c.f;
}
__device__ __forceinline__ ushort4 cvt4(float4 v) {
  ushort4 o; o.x = f2bf(v.x); o.y = f2bf(v.y); o.z = f2bf(v.z); o.w = f2bf(v.w);
  return o;
}

template <int N> __device__ __forceinline__ void vw() {
  if constexpr (N == 4)      asm volatile("s_waitcnt vmcnt(4)" ::: "memory");
  else if constexpr (N == 2) asm volatile("s_waitcnt vmcnt(2)" ::: "memory");
  else if constexpr (N == 0) asm volatile("s_waitcnt vmcnt(0)" ::: "memory");
}

// ---------------------------------------------------------------- prep ------
__global__ __launch_bounds__(256) void prep(const float4* __restrict__ h,
                                            const float4* __restrict__ wq,
                                            const float4* __restrict__ wk,
                                            const float4* __restrict__ wv,
                                            ushort4* __restrict__ hb,
                                            ushort4* __restrict__ wcat) {
  int i = blockIdx.x * 256 + threadIdx.x;  // float4 units
  if (i < 1048576) { hb[i] = cvt4(h[i]); return; }          // h: 4096x1024
  i -= 1048576;
  if (i < 262144) { wcat[i] = cvt4(wq[i]); return; }
  i -= 262144;
  if (i < 262144) { wcat[262144 + i] = cvt4(wk[i]); return; }
  i -= 262144;
  wcat[524288 + i] = cvt4(wv[i]);
}

// -------------------- BK=32, 2-tiles/phase, 5-buffer NT GEMM ----------------
// C[m,n] = sum_k A[m*lda+k] * B[n*1024+k], M=4096, K=1024, BM=128.
// grid 256 = 32 m x 8 n (r15 mapping), 512 thr = 8 waves (2x4).
// Phase p: {reads tile 2p | stage 2p+3 | MFMA | reads 2p+1 | stage 2p+4 |
// MFMA | lgkmcnt(0) | vw<V> | s_barrier | sched_barrier}.  16 phases.
// Safety: read bufs 2p%5,(2p+1)%5 vs write bufs (2p+3)%5,(2p+4)%5 all
// distinct mod 5; per-wave lgkmcnt(0) precedes the phase barrier (WAR);
// tiles 2p+2,2p+3 gated by all waves' vw<V>+barrier at end of phase p.

#define NOPW ((void)0)

#define TILE1(KT, DO_STAGE)                                                  \
  do {                                                                       \
    const u16* Ab = &Als[(KT) % 5][wm * 32 + aoff];                          \
    const u16* Bb = &Bls[(KT) % 5][wn * 32 + aoff];                          \
    bf16x8 af[MI], bv[NI];                                                   \
    _Pragma("unroll") for (int i = 0; i < MI; ++i)                           \
        af[i] = *(const bf16x8*)(Ab + i * 512);                              \
    _Pragma("unroll") for (int j = 0; j < NI; ++j)                           \
        bv[j] = *(const bf16x8*)(Bb + j * 512);                              \
    DO_STAGE;                                                                \
    __builtin_amdgcn_s_setprio(1);                                           \
    _Pragma("unroll") for (int i = 0; i < MI; ++i)                           \
        _Pragma("unroll") for (int j = 0; j < NI; ++j)                       \
            acc[i][j] = __builtin_amdgcn_mfma_f32_16x16x32_bf16(             \
                af[i], bv[j], acc[i][j], 0, 0, 0);                           \
    __builtin_amdgcn_s_setprio(0);                                           \
  } while (0)

#define PHASE2(KT, ST1, ST2, VWAIT)                                          \
  do {                                                                       \
    TILE1(KT, ST1);                                                          \
    TILE1((KT) + 1, ST2);                                                    \
    asm volatile("s_waitcnt lgkmcnt(0)" ::: "memory");                       \
    VWAIT;                                                                   \
    __builtin_amdgcn_s_barrier();                                            \
    __builtin_amdgcn_sched_barrier(0);                                       \
  } while (0)

template <bool BF16_OUT, int BN, int W>
__global__ __launch_bounds__(512, W) void gemmP(const u16* __restrict__ A,
                                                int lda,
                                                const u16* __restrict__ B0,
                                                const u16* __restrict__ B1,
                                                void* __restrict__ Cv,
                                                int N) {
  constexpr int SA = 1;              // A staging insts/thread (BM=128)
  constexpr int SB = BN / 128;       // B staging insts/thread
  constexpr int V  = SA + SB;        // insts/thread per K-tile
  constexpr int MI = 4;              // 64-row wave half
  constexpr int NI = BN / 4 / 16;

  __shared__ u16 Als[5][128 * 32];
  __shared__ u16 Bls[5][BN * 32];
  const int t = threadIdx.x;
  const int lane = t & 63;
  const int wave = t >> 6;                 // 0..7
  const int wm = (wave >> 2) * 64;         // 0 / 64
  const int wn = (wave & 3) * (BN / 4);
  const int lrow = lane & 15;
  const int quad = lane >> 4;

  // r15 mapping: XCD x -> m-tiles {4x..4x+3} x all 8 n-panels.
  const int bid = blockIdx.x;
  const int xcd = bid & 7;
  const int c = bid >> 3;                  // 0..31
  const int m0 = (xcd * 4 + (c >> 3)) * 128;
  const int n0 = (c & 7) * BN;
  const u16* B = (B1 != nullptr && m0 >= 2048) ? B1 : B0;

  // staging: one inst = 16 rows x 32 k = 1 KB; lane l -> row +(l>>2),
  // LDS slot l&3 holds global k-granule (l&3)^((l>>3)&3)  (linear dest).
  const int srow = lane >> 2;
  const int sgk  = (lane & 3) ^ ((lane >> 3) & 3);
  const u16* Ag = A + (size_t)(m0 + wave * (SA * 16) + srow) * lda + sgk * 8;
  const u16* Bg = B + (size_t)(n0 + wave * (SB * 16) + srow) * 1024 + sgk * 8;

  // read swizzle: slot of granule `quad` at row r is quad^((r>>1)&3);
  // row bases are multiples of 16 -> (r>>1)&3 == (lrow>>1)&3.
  const int swz = (lrow >> 1) & 3;
  const int aoff = lrow * 32 + ((quad ^ swz) << 3);

  f32x4 acc[MI][NI];
#pragma unroll
  for (int i = 0; i < MI; ++i)
#pragma unroll
    for (int j = 0; j < NI; ++j) acc[i][j] = {0.f, 0.f, 0.f, 0.f};

  auto stage = [&](int kt) {
    const int buf = kt % 5;
#pragma unroll
    for (int j = 0; j < SA; ++j) {
      const int ch = wave * SA + j;
      async_copy16(&Als[buf][ch * 512 + lane * 8],
                   Ag + (size_t)(j * 16) * lda + kt * 32);
    }
#pragma unroll
    for (int j = 0; j < SB; ++j) {
      const int ch = wave * SB + j;
      async_copy16(&Bls[buf][ch * 512 + lane * 8],
                   Bg + (size_t)(j * 16) * 1024 + kt * 32);
    }
  };

  // prologue: stage tiles 0,1,2 (3V insts); vw<V> -> tiles 0,1 resident,
  // tile 2 still in flight; barrier.
  stage(0); stage(1); stage(2);
  vw<V>();
  __builtin_amdgcn_s_barrier();
  __builtin_amdgcn_sched_barrier(0);

  // steady: 14 phases; phase p reads 2p,2p+1, stages 2p+3,2p+4;
  // vw<V> drains tiles 2p+2,2p+3, leaves 2p+4 in flight.
#pragma unroll 1
  for (int p = 0; p < 14; ++p) {
    PHASE2(2 * p, stage(2 * p + 3), stage(2 * p + 4), vw<V>());
  }
  // p=14: reads 28,29; stage 31 only; drain everything (tiles 30,31).
  PHASE2(28, stage(31), NOPW, vw<0>());
  // p=15: reads 30,31.
  PHASE2(30, NOPW, NOPW, NOPW);

  // C/D layout (verified m89/m91): col = lane&15, row = (lane>>4)*4 + r
  const int crow0 = m0 + wm + quad * 4;
  const int ccol0 = n0 + wn + lrow;
#pragma unroll
  for (int mf = 0; mf < MI; ++mf)
#pragma unroll
    for (int nf = 0; nf < NI; ++nf)
#pragma unroll
      for (int r = 0; r < 4; ++r) {
        const size_t idx = (size_t)(crow0 + mf * 16 + r) * N + ccol0 + nf * 16;
        if (BF16_OUT) ((u16*)Cv)[idx]   = f2bf(acc[mf][nf][r]);
        else          ((float*)Cv)[idx] = acc[mf][nf][r];
      }
}

// --------------------------------------------- Spart = partial K^T V --------
__global__ __launch_bounds__(256) void s_kernel(const u16* __restrict__ QKV,
                                                float* __restrict__ Spart) {
  const int bh = blockIdx.x;
  const int b = bh >> 4, hh = bh & 15;
  const int row0 = b * 2048 + blockIdx.y * 128;
  const u16* Kg = QKV + (size_t)row0 * 3072 + 1024 + hh * 64;

  __shared__ float Ks[64][64];
  __shared__ float Vs[64][64];
  const int t = threadIdx.x;
  const int lr = t >> 2;        // 0..63 row within stage
  const int lc = (t & 3) * 16;  // col group (16 cols)
  const int d1 = (t >> 4) * 4;
  const int d2 = (t & 15) * 4;

  float acc[4][4] = {};

  for (int r0 = 0; r0 < 128; r0 += 64) {
    const u16* kp = Kg + (size_t)(r0 + lr) * 3072 + lc;
    const uint4 kw0 = *(const uint4*)kp;
    const uint4 kw1 = *(const uint4*)(kp + 8);
    const uint4 vw0 = *(const uint4*)(kp + 1024);  // V = K + 1024 cols
    const uint4 vw1 = *(const uint4*)(kp + 1032);
    __syncthreads();  // prev-iter readers done
    float* kd = &Ks[lr][lc];
    *(float4*)(kd)      = float4{bflo(kw0.x), bfhi(kw0.x), bflo(kw0.y), bfhi(kw0.y)};
    *(float4*)(kd + 4)  = float4{bflo(kw0.z), bfhi(kw0.z), bflo(kw0.w), bfhi(kw0.w)};
    *(float4*)(kd + 8)  = float4{bflo(kw1.x), bfhi(kw1.x), bflo(kw1.y), bfhi(kw1.y)};
    *(float4*)(kd + 12) = float4{bflo(kw1.z), bfhi(kw1.z), bflo(kw1.w), bfhi(kw1.w)};
    float* vd = &Vs[lr][lc];
    *(float4*)(vd)      = float4{bflo(vw0.x), bfhi(vw0.x), bflo(vw0.y), bfhi(vw0.y)};
    *(float4*)(vd + 4)  = float4{bflo(vw0.z), bfhi(vw0.z), bflo(vw0.w), bfhi(vw0.w)};
    *(float4*)(vd + 8)  = float4{bflo(vw1.x), bfhi(vw1.x), bflo(vw1.y), bfhi(vw1.y)};
    *(float4*)(vd + 12) = float4{bflo(vw1.z), bfhi(vw1.z), bflo(vw1.w), bfhi(vw1.w)};
    __syncthreads();
#pragma unroll
    for (int r = 0; r < 64; ++r) {
      float kv[4], vv[4];
      *(float4*)kv = *(const float4*)&Ks[r][d1];
      *(float4*)vv = *(const float4*)&Vs[r][d2];
#pragma unroll
      for (int i = 0; i < 4; ++i)
#pragma unroll
        for (int j = 0; j < 4; ++j) acc[i][j] += kv[i] * vv[j];
    }
  }
  float* Sp = Spart + ((size_t)bh * 16 + blockIdx.y) * 4096;
#pragma unroll
  for (int i = 0; i < 4; ++i)
    *(float4*)&Sp[(d1 + i) * 64 + d2] =
        float4{acc[i][0], acc[i][1], acc[i][2], acc[i][3]};
}

// ---------------------------------------------------- S = sum_c Spart -------
__global__ __launch_bounds__(256) void reduce_s(const float4* __restrict__ Spart,
                                                float4* __restrict__ S) {
  const int g = blockIdx.x * 256 + threadIdx.x;  // 0..32767
  const int bh = g >> 10, j = g & 1023;
  const float4* p = Spart + (size_t)bh * 16384 + j;  // 16 chunks * 1024 f4
  float4 a = {0.f, 0.f, 0.f, 0.f};
#pragma unroll
  for (int c = 0; c < 16; ++c) {
    const float4 v = p[(size_t)c * 1024];
    a.x += v.x; a.y += v.y; a.z += v.z; a.w += v.w;
  }
  S[g] = a;
}

// ------------------------------------------- Tt = (S_h Wo_h^T)^T ------------
__global__ __launch_bounds__(256) void t_kernel(const float* __restrict__ S,
                                                const float* __restrict__ Wo,
                                                u16* __restrict__ Tt) {
  const int n0 = blockIdx.x * 128;
  const int hh = blockIdx.y;
  const int b  = blockIdx.z;
  __shared__ float Ss[64][68];
  __shared__ float Ws[128][68];
  const int t = threadIdx.x;
  {
    const float* sg = S + (size_t)(b * 16 + hh) * 4096 + (t >> 2) * 64 + (t & 3) * 16;
    float* sd = &Ss[t >> 2][(t & 3) * 16];
#pragma unroll
    for (int i = 0; i < 4; ++i) *(float4*)(sd + 4 * i) = *(const float4*)(sg + 4 * i);
    const float* wg = Wo + (size_t)(n0 + (t >> 1)) * 1024 + hh * 64 + (t & 1) * 32;
    float* wd = &Ws[t >> 1][(t & 1) * 32];
#pragma unroll
    for (int i = 0; i < 8; ++i) *(float4*)(wd + 4 * i) = *(const float4*)(wg + 4 * i);
  }
  __syncthreads();

  const int td = (t >> 4) * 4;  // d = td..td+3
  const int tn = t & 15;        // n = n0 + tn + 16k
  float acc[4][8] = {};
  for (int jj = 0; jj < 64; jj += 4) {
    float4 sv[4], wv[8];
#pragma unroll
    for (int i = 0; i < 4; ++i) sv[i] = *(const float4*)&Ss[td + i][jj];
#pragma unroll
    for (int k = 0; k < 8; ++k) wv[k] = *(const float4*)&Ws[tn + 16 * k][jj];
#pragma unroll
    for (int i = 0; i < 4; ++i)
#pragma unroll
      for (int k = 0; k < 8; ++k)
        acc[i][k] += sv[i].x * wv[k].x + sv[i].y * wv[k].y +
                     sv[i].z * wv[k].z + sv[i].w * wv[k].w;
  }

  u16* tp = Tt + (size_t)b * 1048576;
#pragma unroll
  for (int k = 0; k < 8; ++k) {
    const int n = n0 + tn + 16 * k;
    ushort4 o;
    o.x = f2bf(acc[0][k]); o.y = f2bf(acc[1][k]);
    o.z = f2bf(acc[2][k]); o.w = f2bf(acc[3][k]);
    *(ushort4*)&tp[(size_t)n * 1024 + hh * 64 + td] = o;
  }
}

// ---------------------------------------------------------------------------
extern "C" void kernel_launch(void* const* d_in, const int* in_sizes, int n_in,
                              void* d_out, int out_size, void* d_ws, size_t ws_size,
                              hipStream_t stream) {
  const float* h  = (const float*)d_in[0];  // (4096, 1024) fp32
  // d_in[1] = key_pe: dead branch in reference, unused.
  const float* Wq = (const float*)d_in[2];
  const float* Wk = (const float*)d_in[3];
  const float* Wv = (const float*)d_in[4];
  const float* Wo = (const float*)d_in[5];

  char* ws = (char*)d_ws;
  u16*   hb    = (u16*)(ws);                    // 4096*1024*2 = 8 MiB @ 0
  u16*   wcat  = (u16*)(ws + (8ull  << 20));    // 3072*1024*2 = 6 MiB
  u16*   QKVb  = (u16*)(ws + (16ull << 20));    // 4096*3072*2 = 24 MiB
  float* S     = (float*)(ws + (40ull << 20));  // 32*64*64*4  = 0.5 MiB
  u16*   Tt    = (u16*)(ws + (41ull << 20));    // 2*1024*1024*2 = 4 MiB
  float* Spart = (float*)(ws + (48ull << 20));  // 512*64*64*4 = 8 MiB
  // total ws use: 56 MiB (ws_size = 256 MiB)

  prep<<<7168, 256, 0, stream>>>((const float4*)h, (const float4*)Wq,
                                 (const float4*)Wk, (const float4*)Wv,
                                 (ushort4*)hb, (ushort4*)wcat);
  // QKVb = hb @ wcat^T : (4096 x 3072), K=1024, 256 blocks, 8 waves,
  // 160KB LDS -> 1 block/CU, single full dispatch round.
  gemmP<true, 384, 2><<<256, 512, 0, stream>>>(hb, 1024, wcat, nullptr,
                                               QKVb, 3072);
  s_kernel<<<dim3(32, 16), 256, 0, stream>>>(QKVb, Spart);
  reduce_s<<<128, 256, 0, stream>>>((const float4*)Spart, (float4*)S);
  t_kernel<<<dim3(8, 16, 2), 256, 0, stream>>>(S, Wo, Tt);
  // out = Q @ Tt_b^T : (4096 x 1024), K=1024, 256 blocks, 80KB LDS.
  gemmP<false, 128, 4><<<256, 512, 0, stream>>>(QKVb, 3072, Tt,
                                                Tt + 1048576, d_out, 1024);
}